// Round 5
// baseline (372.041 us; speedup 1.0000x reference)
//
#include <hip/hip_runtime.h>
#include <hip/hip_bf16.h>

typedef __attribute__((ext_vector_type(8))) short bf16x8;
typedef __attribute__((ext_vector_type(4))) short bf16x4;
typedef __attribute__((ext_vector_type(4))) float f32x4;

constexpr int NT   = 512;   // tiles
constexpr int NP   = 512;   // points (M)
constexpr int DIN  = 256;   // K
constexpr int DOUT = 256;   // N
constexpr int BN   = 128;   // N cols per block (half a channel)

__device__ __forceinline__ short f2bf(float f) {
  __hip_bfloat16 h = __float2bfloat16(f);
  return __builtin_bit_cast(short, h);
}

__device__ __forceinline__ bf16x8 cvt8(float4 a, float4 b) {
  bf16x8 r;
  r[0] = f2bf(a.x); r[1] = f2bf(a.y); r[2] = f2bf(a.z); r[3] = f2bf(a.w);
  r[4] = f2bf(b.x); r[5] = f2bf(b.y); r[6] = f2bf(b.z); r[7] = f2bf(b.w);
  return r;
}

// Ws is [n][k] bf16 (K-contiguous per row), 128x256 = 64 KB.
// XOR-swizzle k in 8-element (16 B) granules by (n&7): the b-fragment
// ds_read_b128 (16 lanes at consecutive n, same k) lands on 8 distinct
// 16 B slots -> 2-way bank aliasing (free).
__device__ __forceinline__ int wswz(int n, int k) {
  return n * DIN + (k ^ ((n & 7) << 3));
}

__global__ __launch_bounds__(512, 4) void adaptive_linear_ws2(
    const float* __restrict__ x,     // [NT][NP][DIN]
    const int*   __restrict__ idx,   // [NT]
    const float* __restrict__ w,     // [CH][DIN][DOUT]
    const float* __restrict__ bias,  // [DOUT]
    float*       __restrict__ out)   // [NT][NP][DOUT]
{
  __shared__ short Ws[BN * DIN];     // transposed half-channel, bf16, 64 KB

  const int tid   = threadIdx.x;
  const int bid   = blockIdx.x;
  const int t     = bid >> 1;
  const int nhalf = bid & 1;

  const int c = idx[t];
  const float* xb = x   + (size_t)t * NP * DIN;
  const float* wb = w   + (size_t)c * DIN * DOUT + nhalf * BN;
  float*       ob = out + (size_t)t * NP * DOUT + nhalf * BN;

  // ---- stage W[c][:, nhalf*128 .. +128) (f32 [K][N]) -> Ws (bf16 [n][k]), once
  // kgroup in low tid bits spreads the transpose ds_writes across banks.
  {
    const int kgroup = tid & 15;       // k sub-offset within a 64-k slab
    const int n4     = (tid >> 4) * 4; // 0..124
    #pragma unroll
    for (int kk = 0; kk < 4; ++kk) {
      const int k0 = kk * 64 + kgroup * 4;
      const float* src = wb + (size_t)k0 * DOUT + n4;
      const float4 v0 = *reinterpret_cast<const float4*>(src + 0 * DOUT);
      const float4 v1 = *reinterpret_cast<const float4*>(src + 1 * DOUT);
      const float4 v2 = *reinterpret_cast<const float4*>(src + 2 * DOUT);
      const float4 v3 = *reinterpret_cast<const float4*>(src + 3 * DOUT);
      bf16x4 h0 = { f2bf(v0.x), f2bf(v1.x), f2bf(v2.x), f2bf(v3.x) };
      bf16x4 h1 = { f2bf(v0.y), f2bf(v1.y), f2bf(v2.y), f2bf(v3.y) };
      bf16x4 h2 = { f2bf(v0.z), f2bf(v1.z), f2bf(v2.z), f2bf(v3.z) };
      bf16x4 h3 = { f2bf(v0.w), f2bf(v1.w), f2bf(v2.w), f2bf(v3.w) };
      *reinterpret_cast<bf16x4*>(&Ws[wswz(n4 + 0, k0)]) = h0;
      *reinterpret_cast<bf16x4*>(&Ws[wswz(n4 + 1, k0)]) = h1;
      *reinterpret_cast<bf16x4*>(&Ws[wswz(n4 + 2, k0)]) = h2;
      *reinterpret_cast<bf16x4*>(&Ws[wswz(n4 + 3, k0)]) = h3;
    }
  }
  __syncthreads();   // the ONLY barrier in the kernel

  // ---- 8 waves as 4 (M) x 2 (N); each wave owns a 64x64 output sub-tile
  const int l   = tid & 63;
  const int wid = tid >> 6;
  const int wm  = wid >> 1;          // 0..3
  const int wn  = wid & 1;           // 0..1
  const int lrow = l & 15;
  const int lk   = l >> 4;           // 0..3

  float bv[4];
  #pragma unroll
  for (int fn = 0; fn < 4; ++fn)
    bv[fn] = bias[nhalf * BN + wn * 64 + fn * 16 + lrow];

  // 2 M-chunks of 256 rows; full K=256 per chunk; no barriers.
  for (int ch = 0; ch < 2; ++ch) {
    const int mb = ch * 256 + wm * 64;
    f32x4 acc[4][4] = {};

    // raw f32 buffer for the A fragments (one K-step ahead)
    float4 r0[4], r1[4];
    {
      const float* p0 = xb + (size_t)(mb + lrow) * DIN + lk * 8;
      #pragma unroll
      for (int fm = 0; fm < 4; ++fm) {
        const float* p = p0 + (size_t)fm * 16 * DIN;
        r0[fm] = *reinterpret_cast<const float4*>(p);
        r1[fm] = *reinterpret_cast<const float4*>(p + 4);
      }
    }

    #pragma unroll
    for (int ks = 0; ks < 8; ++ks) {
      bf16x8 a[4];
      #pragma unroll
      for (int fm = 0; fm < 4; ++fm) a[fm] = cvt8(r0[fm], r1[fm]);

      if (ks < 7) {   // issue next K-step's loads before this step's MFMAs
        const float* p0 = xb + (size_t)(mb + lrow) * DIN + (ks + 1) * 32 + lk * 8;
        #pragma unroll
        for (int fm = 0; fm < 4; ++fm) {
          const float* p = p0 + (size_t)fm * 16 * DIN;
          r0[fm] = *reinterpret_cast<const float4*>(p);
          r1[fm] = *reinterpret_cast<const float4*>(p + 4);
        }
      }

      bf16x8 b[4];
      #pragma unroll
      for (int fn = 0; fn < 4; ++fn)
        b[fn] = *reinterpret_cast<const bf16x8*>(
            &Ws[wswz(wn * 64 + fn * 16 + lrow, ks * 32 + lk * 8)]);

      #pragma unroll
      for (int fm = 0; fm < 4; ++fm)
        #pragma unroll
        for (int fn = 0; fn < 4; ++fn)
          acc[fm][fn] = __builtin_amdgcn_mfma_f32_16x16x32_bf16(
              a[fm], b[fn], acc[fm][fn], 0, 0, 0);
    }

    // ---- epilogue for this chunk: add bias, nontemporal f32 stores
    #pragma unroll
    for (int fm = 0; fm < 4; ++fm) {
      const int r0w = mb + fm * 16 + lk * 4;
      #pragma unroll
      for (int fn = 0; fn < 4; ++fn) {
        const int col = wn * 64 + fn * 16 + lrow;
        float* op = ob + (size_t)r0w * DOUT + col;
        #pragma unroll
        for (int rr = 0; rr < 4; ++rr)
          __builtin_nontemporal_store(acc[fm][fn][rr] + bv[fn], op + (size_t)rr * DOUT);
      }
    }
  }
}

extern "C" void kernel_launch(void* const* d_in, const int* in_sizes, int n_in,
                              void* d_out, int out_size, void* d_ws, size_t ws_size,
                              hipStream_t stream) {
  const float* x    = (const float*)d_in[0];
  const int*   idx  = (const int*)d_in[1];
  const float* w    = (const float*)d_in[2];
  const float* bias = (const float*)d_in[3];
  float* out = (float*)d_out;

  adaptive_linear_ws2<<<NT * 2, 512, 0, stream>>>(x, idx, w, bias, out);
}

// Round 6
// 149.081 us; speedup vs baseline: 2.4956x; 2.4956x over previous
//
#include <hip/hip_runtime.h>
#include <hip/hip_bf16.h>

typedef __attribute__((ext_vector_type(8))) short bf16x8;
typedef __attribute__((ext_vector_type(4))) short bf16x4;
typedef __attribute__((ext_vector_type(4))) float f32x4;

constexpr int NT   = 512;   // tiles
constexpr int NP   = 512;   // points (M)
constexpr int DIN  = 256;   // K
constexpr int DOUT = 256;   // N

__device__ __forceinline__ short f2bf(float f) {
  __hip_bfloat16 h = __float2bfloat16(f);
  return __builtin_bit_cast(short, h);
}

// Ws: [n=256][k=256] bf16 (k-contiguous rows), 128 KB.
// XOR-swizzle k in 8-elem (16 B) granules by (n>>1)&7: B-frag ds_read_b128
// (16 lanes at consecutive n, fixed k) -> granule changes every 2 lanes ->
// 2-way (free).
__device__ __forceinline__ int wsw(int n, int k) {
  return n * DIN + (k ^ (((n >> 1) & 7) << 3));
}

// Xs: [m=128][k=64] bf16, 16 KB. XOR-swizzle by (m&7): A-frag ds_read_b128
// (16 lanes at consecutive m, fixed k) -> 8 granules over 8 rows -> 2-way.
__device__ __forceinline__ int xsw(int m, int k) {
  return m * 64 + (k ^ ((m & 7) << 3));
}

__global__ __launch_bounds__(512, 2) void adaptive_linear_v3(
    const float* __restrict__ x,     // [NT][NP][DIN]
    const int*   __restrict__ idx,   // [NT]
    const float* __restrict__ w,     // [CH][DIN][DOUT]
    const float* __restrict__ bias,  // [DOUT]
    float*       __restrict__ out)   // [NT][NP][DOUT]
{
  __shared__ short Ws[DOUT * DIN];   // 128 KB
  __shared__ short Xs[128 * 64];     // 16 KB   (total 144 KB, 1 block/CU)

  const int tid = threadIdx.x;
  const int t   = blockIdx.x;

  const int c = idx[t];
  const float* xb = x   + (size_t)t * NP * DIN;
  const float* wb = w   + (size_t)c * DIN * DOUT;
  float*       ob = out + (size_t)t * NP * DOUT;

  // ---- staging-thread decompositions -----------------------------------
  // W: wave wv streams 8 consecutive k-rows; 64 lanes x 16 B = one full
  //    1 KB row per load instr (perfectly coalesced).
  const int wl = tid & 63;           // n4 = wl*4
  const int wv = tid >> 6;           // k-subgroup 0..7
  // x: per instr, 4 lanes x 16 B cover one 64-B line; 16 rows per wave.
  const int xrow = tid >> 2;         // 0..127
  const int xo   = (tid & 3) * 4;    // float offset

  f32x4 wr[8];                       // W stage regs (live only during chunk 0)
  f32x4 xr[4];                       // x stage regs

  auto load_w = [&](int ss) {        // issue global loads for W slab ss
    const float* ws = wb + (size_t)(ss * 64 + wv * 8) * DOUT + wl * 4;
    #pragma unroll
    for (int q = 0; q < 8; ++q)
      wr[q] = *reinterpret_cast<const f32x4*>(ws + (size_t)q * DOUT);
  };
  auto write_w = [&](int ss) {       // cvt + transposed LDS write
    #pragma unroll
    for (int h = 0; h < 2; ++h) {
      const int k0 = ss * 64 + wv * 8 + h * 4;
      #pragma unroll
      for (int j = 0; j < 4; ++j) {
        bf16x4 v = { f2bf(wr[h*4+0][j]), f2bf(wr[h*4+1][j]),
                     f2bf(wr[h*4+2][j]), f2bf(wr[h*4+3][j]) };
        *reinterpret_cast<bf16x4*>(&Ws[wsw(wl * 4 + j, k0)]) = v;
      }
    }
  };
  auto load_x = [&](int s) {         // issue global loads for step s
    const int c4 = s >> 2, ks = s & 3;
    const float* xs = xb + (size_t)(c4 * 128 + xrow) * DIN + ks * 64 + xo;
    #pragma unroll
    for (int i = 0; i < 4; ++i)
      xr[i] = *reinterpret_cast<const f32x4*>(xs + i * 16);
  };
  auto write_x = [&]() {             // cvt + LDS write (k-local layout)
    #pragma unroll
    for (int i = 0; i < 4; ++i) {
      const int k0 = i * 16 + xo;
      bf16x4 v = { f2bf(xr[i][0]), f2bf(xr[i][1]),
                   f2bf(xr[i][2]), f2bf(xr[i][3]) };
      *reinterpret_cast<bf16x4*>(&Xs[xsw(xrow, k0)]) = v;
    }
  };

  // ---- wave decomposition: 2 (M) x 4 (N); wave owns 64 x 64 ------------
  const int l    = tid & 63;
  const int wid  = tid >> 6;
  const int wm   = wid >> 2;         // 0..1
  const int wn   = wid & 3;          // 0..3
  const int lrow = l & 15;
  const int lk   = l >> 4;           // 0..3

  float bv[4];
  #pragma unroll
  for (int fn = 0; fn < 4; ++fn)
    bv[fn] = bias[wn * 64 + fn * 16 + lrow];

  // ---- prologue: W slab 0 + x step 0 -----------------------------------
  load_w(0);
  load_x(0);
  write_w(0);
  write_x();
  __syncthreads();

  f32x4 acc[4][4] = {};

  for (int c4 = 0; c4 < 4; ++c4) {        // M-chunks of 128 rows
    #pragma unroll
    for (int ks = 0; ks < 4; ++ks) {      // K-steps of 64
      const int s = c4 * 4 + ks;

      // issue next step's loads BEFORE compute — they fly during the MFMAs
      if (s < 15) load_x(s + 1);
      if (s < 3)  load_w(s + 1);

      // compute: 2 k-chunks of 32
      #pragma unroll
      for (int kc = 0; kc < 2; ++kc) {
        const int kb = kc * 32 + lk * 8;
        bf16x8 a[4], b[4];
        #pragma unroll
        for (int fm = 0; fm < 4; ++fm)
          a[fm] = *reinterpret_cast<const bf16x8*>(
              &Xs[xsw(wm * 64 + fm * 16 + lrow, kb)]);
        #pragma unroll
        for (int fn = 0; fn < 4; ++fn)
          b[fn] = *reinterpret_cast<const bf16x8*>(
              &Ws[wsw(wn * 64 + fn * 16 + lrow, ks * 64 + kb)]);
        #pragma unroll
        for (int fm = 0; fm < 4; ++fm)
          #pragma unroll
          for (int fn = 0; fn < 4; ++fn)
            acc[fm][fn] = __builtin_amdgcn_mfma_f32_16x16x32_bf16(
                a[fm], b[fn], acc[fm][fn], 0, 0, 0);
      }

      if (ks == 3) {
        // epilogue for this chunk: add bias, nontemporal stores
        #pragma unroll
        for (int fm = 0; fm < 4; ++fm) {
          const int r0w = c4 * 128 + wm * 64 + fm * 16 + lk * 4;
          #pragma unroll
          for (int fn = 0; fn < 4; ++fn) {
            const int col = wn * 64 + fn * 16 + lrow;
            float* op = ob + (size_t)r0w * DOUT + col;
            #pragma unroll
            for (int rr = 0; rr < 4; ++rr)
              __builtin_nontemporal_store(acc[fm][fn][rr] + bv[fn],
                                          op + (size_t)rr * DOUT);
          }
        }
        #pragma unroll
        for (int fm = 0; fm < 4; ++fm)
          #pragma unroll
          for (int fn = 0; fn < 4; ++fn)
            acc[fm][fn] = f32x4{0.f, 0.f, 0.f, 0.f};
      }

      __syncthreads();                    // Xs fully consumed
      if (s < 15) write_x();              // cvt + write step s+1
      if (s < 3)  write_w(s + 1);         // chunk-0 only: next W slab
      __syncthreads();                    // Xs(s+1)/Ws ready
    }
  }
}

extern "C" void kernel_launch(void* const* d_in, const int* in_sizes, int n_in,
                              void* d_out, int out_size, void* d_ws, size_t ws_size,
                              hipStream_t stream) {
  const float* x    = (const float*)d_in[0];
  const int*   idx  = (const int*)d_in[1];
  const float* w    = (const float*)d_in[2];
  const float* bias = (const float*)d_in[3];
  float* out = (float*)d_out;

  adaptive_linear_v3<<<NT, 512, 0, stream>>>(x, idx, w, bias, out);
}

// Round 7
// 136.315 us; speedup vs baseline: 2.7293x; 1.0936x over previous
//
#include <hip/hip_runtime.h>
#include <hip/hip_bf16.h>

typedef __attribute__((ext_vector_type(8))) short bf16x8;
typedef __attribute__((ext_vector_type(4))) short bf16x4;
typedef __attribute__((ext_vector_type(4))) float f32x4;

constexpr int NT   = 512;   // tiles
constexpr int NP   = 512;   // points (M)
constexpr int DIN  = 256;   // K
constexpr int DOUT = 256;   // N

__device__ __forceinline__ short f2bf(float f) {
  __hip_bfloat16 h = __float2bfloat16(f);
  return __builtin_bit_cast(short, h);
}

// Ws: [n=256][k=256] bf16, 128 KB. Granule = 8 elem (16 B).
// g(n) = (n ^ (n>>2)) & 7: B-frag reads (16 consecutive n, fixed k) spread
// evenly (floor); transpose writes (n = 4*wl + j) get 8 distinct granules
// per 8 lanes (8-way, was 16-way with (n>>1)&7).
__device__ __forceinline__ int wsw(int n, int k) {
  return n * DIN + (k ^ (((n ^ (n >> 2)) & 7) << 3));
}

// Xs: [m=128][k=64] bf16, 16 KB per buffer. A-frag reads free (2-way);
// staging writes at the b64 floor.
__device__ __forceinline__ int xsw(int m, int k) {
  return m * 64 + (k ^ ((m & 7) << 3));
}

__global__ __launch_bounds__(512, 2) void adaptive_linear_v4(
    const float* __restrict__ x,     // [NT][NP][DIN]
    const int*   __restrict__ idx,   // [NT]
    const float* __restrict__ w,     // [CH][DIN][DOUT]
    const float* __restrict__ bias,  // [DOUT]
    float*       __restrict__ out)   // [NT][NP][DOUT]
{
  __shared__ short Ws[DOUT * DIN];     // 128 KB
  __shared__ short Xs[2][128 * 64];    // 2 x 16 KB  (total 160 KiB exactly)

  const int tid = threadIdx.x;
  const int t   = blockIdx.x;

  const int c = idx[t];
  const float* xb = x   + (size_t)t * NP * DIN;
  const float* wb = w   + (size_t)c * DIN * DOUT;
  float*       ob = out + (size_t)t * NP * DOUT;

  // ---- staging decompositions ------------------------------------------
  // W: wave wv streams 8 consecutive k-rows; 64 lanes x 16 B = 1 KB row.
  const int wl = tid & 63;
  const int wv = tid >> 6;
  // x: 4 lanes x 16 B per 64-B row segment; 16 rows per wave per instr.
  const int xrow = tid >> 2;           // 0..127
  const int xo   = (tid & 3) * 4;      // float offset within 64-elem slab

  f32x4 wr[8];                         // W stage regs (single buffer)
  f32x4 xr[2][4];                      // x stage regs (double buffer)

  auto load_w = [&](int ss) {
    const float* ws = wb + (size_t)(ss * 64 + wv * 8) * DOUT + wl * 4;
    #pragma unroll
    for (int q = 0; q < 8; ++q)
      wr[q] = *reinterpret_cast<const f32x4*>(ws + (size_t)q * DOUT);
  };
  auto write_w = [&](int ss) {         // cvt + transposed LDS write
    #pragma unroll
    for (int h = 0; h < 2; ++h) {
      const int k0 = ss * 64 + wv * 8 + h * 4;
      #pragma unroll
      for (int j = 0; j < 4; ++j) {
        bf16x4 v = { f2bf(wr[h*4+0][j]), f2bf(wr[h*4+1][j]),
                     f2bf(wr[h*4+2][j]), f2bf(wr[h*4+3][j]) };
        *reinterpret_cast<bf16x4*>(&Ws[wsw(wl * 4 + j, k0)]) = v;
      }
    }
  };
  auto load_x = [&](int s, int p) {    // issue globals for step s into xr[p]
    const int cc = s >> 2, kk = s & 3;
    const float* xs = xb + (size_t)(cc * 128 + xrow) * DIN + kk * 64 + xo;
    #pragma unroll
    for (int i = 0; i < 4; ++i)
      xr[p][i] = *reinterpret_cast<const f32x4*>(xs + i * 16);
  };
  auto write_x = [&](int p, int b) {   // cvt + LDS write into Xs[b]
    #pragma unroll
    for (int i = 0; i < 4; ++i) {
      const int k0 = i * 16 + xo;
      bf16x4 v = { f2bf(xr[p][i][0]), f2bf(xr[p][i][1]),
                   f2bf(xr[p][i][2]), f2bf(xr[p][i][3]) };
      *reinterpret_cast<bf16x4*>(&Xs[b][xsw(xrow, k0)]) = v;
    }
  };

  // ---- wave decomposition: 2 (M) x 4 (N); wave owns 64 x 64 ------------
  const int l    = tid & 63;
  const int wid  = tid >> 6;
  const int wm   = wid >> 2;           // 0..1
  const int wn   = wid & 3;            // 0..3
  const int lrow = l & 15;
  const int lk   = l >> 4;             // 0..3

  float bv[4];
  #pragma unroll
  for (int fn = 0; fn < 4; ++fn)
    bv[fn] = bias[wn * 64 + fn * 16 + lrow];

  // ---- prologue --------------------------------------------------------
  load_w(0);
  load_x(0, 0);
  write_w(0);            // compiler inserts the vmcnt wait
  write_x(0, 0);         // Xs[0] <- x(0)
  load_w(1);
  load_x(1, 1);          // xr[1] <- x(1)
  __syncthreads();

  f32x4 acc[4][4] = {};

  for (int c4 = 0; c4 < 4; ++c4) {       // M-chunks of 128 rows
    #pragma unroll
    for (int ks = 0; ks < 4; ++ks) {     // K-steps of 64; s = c4*4+ks
      const int s = c4 * 4 + ks;

      // 1. issue x loads for step s+2 into xr[ks&1] (earliest point)
      if (s < 14) load_x(s + 2, ks & 1);

      // 2. publish x(s+1) into the other LDS buffer (no reader conflict)
      if (s < 15) write_x((ks + 1) & 1, (ks + 1) & 1);

      // 3. W pipeline, chunk 0 only: write slab ks+1, then load slab ks+2
      if (c4 == 0 && ks < 3) {
        write_w(ks + 1);
        if (ks < 2) load_w(ks + 2);
      }

      // 4. compute from Xs[ks&1] and Ws k-range ks*64
      #pragma unroll
      for (int kc = 0; kc < 2; ++kc) {
        const int kb = kc * 32 + lk * 8;
        bf16x8 a[4], b[4];
        #pragma unroll
        for (int fm = 0; fm < 4; ++fm)
          a[fm] = *reinterpret_cast<const bf16x8*>(
              &Xs[ks & 1][xsw(wm * 64 + fm * 16 + lrow, kb)]);
        #pragma unroll
        for (int fn = 0; fn < 4; ++fn)
          b[fn] = *reinterpret_cast<const bf16x8*>(
              &Ws[wsw(wn * 64 + fn * 16 + lrow, ks * 64 + kb)]);
        #pragma unroll
        for (int fm = 0; fm < 4; ++fm)
          #pragma unroll
          for (int fn = 0; fn < 4; ++fn)
            acc[fm][fn] = __builtin_amdgcn_mfma_f32_16x16x32_bf16(
                a[fm], b[fn], acc[fm][fn], 0, 0, 0);
      }

      // 5. per-chunk epilogue: add bias, plain f32 stores
      if (ks == 3) {
        #pragma unroll
        for (int fm = 0; fm < 4; ++fm) {
          const int r0w = c4 * 128 + wm * 64 + fm * 16 + lk * 4;
          #pragma unroll
          for (int fn = 0; fn < 4; ++fn) {
            const int col = wn * 64 + fn * 16 + lrow;
            float* op = ob + (size_t)r0w * DOUT + col;
            #pragma unroll
            for (int rr = 0; rr < 4; ++rr)
              op[(size_t)rr * DOUT] = acc[fm][fn][rr] + bv[fn];
          }
        }
        #pragma unroll
        for (int fm = 0; fm < 4; ++fm)
          #pragma unroll
          for (int fn = 0; fn < 4; ++fn)
            acc[fm][fn] = f32x4{0.f, 0.f, 0.f, 0.f};
      }

      if (s < 15) __syncthreads();       // single barrier per K-step
    }
  }
}

extern "C" void kernel_launch(void* const* d_in, const int* in_sizes, int n_in,
                              void* d_out, int out_size, void* d_ws, size_t ws_size,
                              hipStream_t stream) {
  const float* x    = (const float*)d_in[0];
  const int*   idx  = (const int*)d_in[1];
  const float* w    = (const float*)d_in[2];
  const float* bias = (const float*)d_in[3];
  float* out = (float*)d_out;

  adaptive_linear_v4<<<NT, 512, 0, stream>>>(x, idx, w, bias, out);
}

// Round 8
// 135.986 us; speedup vs baseline: 2.7359x; 1.0024x over previous
//
#include <hip/hip_runtime.h>
#include <hip/hip_bf16.h>

typedef __attribute__((ext_vector_type(8))) short bf16x8;
typedef __attribute__((ext_vector_type(4))) short bf16x4;
typedef __attribute__((ext_vector_type(4))) float f32x4;

constexpr int NT   = 512;   // tiles
constexpr int NP   = 512;   // points (M)
constexpr int DIN  = 256;   // K
constexpr int DOUT = 256;   // N

__device__ __forceinline__ short f2bf(float f) {
  __hip_bfloat16 h = __float2bfloat16(f);
  return __builtin_bit_cast(short, h);
}

// Workgroup barrier WITHOUT the vmcnt(0) drain __syncthreads() implies.
// LDS producer/consumer visibility needs only lgkmcnt(0); global loads and
// stores stay in flight across it (T4 counted-vmcnt falls out of the
// compiler's register-dependency waits at the consumer).
__device__ __forceinline__ void wg_barrier() {
  asm volatile("s_waitcnt lgkmcnt(0)" ::: "memory");
  __builtin_amdgcn_s_barrier();
  __builtin_amdgcn_sched_barrier(0);
}

// Ws: [n=256][k=256] bf16, 128 KB. Granule = 8 elem (16 B).
// g(n) = (n ^ (n>>2)) & 7: B-frag reads at the 2-way floor; transpose
// writes 8-way.
__device__ __forceinline__ int wsw(int n, int k) {
  return n * DIN + (k ^ (((n ^ (n >> 2)) & 7) << 3));
}

// Xs: [m=128][k=64] bf16, 16 KB per buffer. Reads and writes ~2-way.
__device__ __forceinline__ int xsw(int m, int k) {
  return m * 64 + (k ^ ((m & 7) << 3));
}

__global__ __launch_bounds__(512, 2) void adaptive_linear_v5(
    const float* __restrict__ x,     // [NT][NP][DIN]
    const int*   __restrict__ idx,   // [NT]
    const float* __restrict__ w,     // [CH][DIN][DOUT]
    const float* __restrict__ bias,  // [DOUT]
    float*       __restrict__ out)   // [NT][NP][DOUT]
{
  __shared__ short Ws[DOUT * DIN];     // 128 KB
  __shared__ short Xs[2][128 * 64];    // 2 x 16 KB  (total 160 KiB exactly)

  const int tid = threadIdx.x;
  const int t   = blockIdx.x;

  const int c = idx[t];
  const float* xb = x   + (size_t)t * NP * DIN;
  const float* wb = w   + (size_t)c * DIN * DOUT;
  float*       ob = out + (size_t)t * NP * DOUT;

  // ---- staging decompositions ------------------------------------------
  const int wl = tid & 63;             // W: n4 = wl*4
  const int wv = tid >> 6;             // W: k-subgroup 0..7
  const int xrow = tid >> 2;           // x: 0..127
  const int xo   = (tid & 3) * 4;      // x: float offset within 64-elem slab

  f32x4 wr[8];                         // W stage regs
  f32x4 xr[2][4];                      // x stage regs (double buffer)

  auto load_w = [&](int ss) {
    const float* ws = wb + (size_t)(ss * 64 + wv * 8) * DOUT + wl * 4;
    #pragma unroll
    for (int q = 0; q < 8; ++q)
      wr[q] = *reinterpret_cast<const f32x4*>(ws + (size_t)q * DOUT);
  };
  auto write_w = [&](int ss) {         // cvt + transposed LDS write
    #pragma unroll
    for (int h = 0; h < 2; ++h) {
      const int k0 = ss * 64 + wv * 8 + h * 4;
      #pragma unroll
      for (int j = 0; j < 4; ++j) {
        bf16x4 v = { f2bf(wr[h*4+0][j]), f2bf(wr[h*4+1][j]),
                     f2bf(wr[h*4+2][j]), f2bf(wr[h*4+3][j]) };
        *reinterpret_cast<bf16x4*>(&Ws[wsw(wl * 4 + j, k0)]) = v;
      }
    }
  };
  auto load_x = [&](int s, int p) {    // issue globals for step s into xr[p]
    const int cc = s >> 2, kk = s & 3;
    const float* xs = xb + (size_t)(cc * 128 + xrow) * DIN + kk * 64 + xo;
    #pragma unroll
    for (int i = 0; i < 4; ++i)
      xr[p][i] = *reinterpret_cast<const f32x4*>(xs + i * 16);
  };
  auto write_x = [&](int p, int b) {   // cvt + LDS write into Xs[b]
    #pragma unroll
    for (int i = 0; i < 4; ++i) {
      const int k0 = i * 16 + xo;
      bf16x4 v = { f2bf(xr[p][i][0]), f2bf(xr[p][i][1]),
                   f2bf(xr[p][i][2]), f2bf(xr[p][i][3]) };
      *reinterpret_cast<bf16x4*>(&Xs[b][xsw(xrow, k0)]) = v;
    }
  };

  // ---- wave decomposition: 2 (M) x 4 (N); wave owns 64 x 64 ------------
  const int l    = tid & 63;
  const int wid  = tid >> 6;
  const int wm   = wid >> 2;           // 0..1
  const int wn   = wid & 3;            // 0..3
  const int lrow = l & 15;
  const int lk   = l >> 4;             // 0..3

  float bv[4];
  #pragma unroll
  for (int fn = 0; fn < 4; ++fn)
    bv[fn] = bias[wn * 64 + fn * 16 + lrow];

  // ---- prologue --------------------------------------------------------
  load_w(0);
  load_x(0, 0);
  write_w(0);            // counted vmcnt wait on wr only
  write_x(0, 0);         // Xs[0] <- x(0)
  load_w(1);
  load_x(1, 1);          // xr[1] <- x(1), stays in flight across the barrier
  wg_barrier();

  f32x4 acc[4][4] = {};

  for (int c4 = 0; c4 < 4; ++c4) {       // M-chunks of 128 rows
    #pragma unroll
    for (int ks = 0; ks < 4; ++ks) {     // K-steps of 64; s = c4*4+ks
      const int s = c4 * 4 + ks;

      // 1. issue x loads for step s+2 (consumed next step -> ~1.5 steps in flight)
      if (s < 14) load_x(s + 2, ks & 1);

      // 2. publish x(s+1) into the other LDS buffer (no reader conflict)
      if (s < 15) write_x((ks + 1) & 1, (ks + 1) & 1);

      // 3. W pipeline, chunk 0 only: write slab ks+1, then load slab ks+2
      if (c4 == 0 && ks < 3) {
        write_w(ks + 1);
        if (ks < 2) load_w(ks + 2);
      }

      // 4. compute from Xs[ks&1] and Ws k-range ks*64
      #pragma unroll
      for (int kc = 0; kc < 2; ++kc) {
        const int kb = kc * 32 + lk * 8;
        bf16x8 a[4], b[4];
        #pragma unroll
        for (int fm = 0; fm < 4; ++fm)
          a[fm] = *reinterpret_cast<const bf16x8*>(
              &Xs[ks & 1][xsw(wm * 64 + fm * 16 + lrow, kb)]);
        #pragma unroll
        for (int fn = 0; fn < 4; ++fn)
          b[fn] = *reinterpret_cast<const bf16x8*>(
              &Ws[wsw(wn * 64 + fn * 16 + lrow, ks * 64 + kb)]);
        #pragma unroll
        for (int fm = 0; fm < 4; ++fm)
          #pragma unroll
          for (int fn = 0; fn < 4; ++fn)
            acc[fm][fn] = __builtin_amdgcn_mfma_f32_16x16x32_bf16(
                a[fm], b[fn], acc[fm][fn], 0, 0, 0);
      }

      // 5. per-chunk epilogue: add bias, plain f32 stores (never drained)
      if (ks == 3) {
        #pragma unroll
        for (int fm = 0; fm < 4; ++fm) {
          const int r0w = c4 * 128 + wm * 64 + fm * 16 + lk * 4;
          #pragma unroll
          for (int fn = 0; fn < 4; ++fn) {
            const int col = wn * 64 + fn * 16 + lrow;
            float* op = ob + (size_t)r0w * DOUT + col;
            #pragma unroll
            for (int rr = 0; rr < 4; ++rr)
              op[(size_t)rr * DOUT] = acc[fm][fn][rr] + bv[fn];
          }
        }
        #pragma unroll
        for (int fm = 0; fm < 4; ++fm)
          #pragma unroll
          for (int fn = 0; fn < 4; ++fn)
            acc[fm][fn] = f32x4{0.f, 0.f, 0.f, 0.f};
      }

      if (s < 15) wg_barrier();          // lgkm-only: loads/stores stay in flight
    }
  }
}

extern "C" void kernel_launch(void* const* d_in, const int* in_sizes, int n_in,
                              void* d_out, int out_size, void* d_ws, size_t ws_size,
                              hipStream_t stream) {
  const float* x    = (const float*)d_in[0];
  const int*   idx  = (const int*)d_in[1];
  const float* w    = (const float*)d_in[2];
  const float* bias = (const float*)d_in[3];
  float* out = (float*)d_out;

  adaptive_linear_v5<<<NT, 512, 0, stream>>>(x, idx, w, bias, out);
}